// Round 2
// baseline (547.119 us; speedup 1.0000x reference)
//
#include <hip/hip_runtime.h>
#include <math.h>

#define Bc 16
#define Nc 4096

typedef __attribute__((ext_vector_type(8))) short short8;
typedef __attribute__((ext_vector_type(4))) float floatx4;

#define VMWAIT(n) asm volatile("s_waitcnt vmcnt(" #n ")" ::: "memory")
#define LGKM0     asm volatile("s_waitcnt lgkmcnt(0)" ::: "memory")
#define CFENCE    asm volatile("" ::: "memory")
#define BARRIER   __builtin_amdgcn_s_barrier()

__device__ __forceinline__ unsigned short f2bf(float f) {
    union { float f; unsigned int u; } v; v.f = f;
    unsigned int u = v.u;
    return (unsigned short)((u + 0x7fffu + ((u >> 16) & 1u)) >> 16);
}
__device__ __forceinline__ float bf2f(unsigned short u) {
    union { unsigned int u; float f; } v; v.u = ((unsigned int)u) << 16;
    return v.f;
}

// branch-free exact-enough gelu: erf via Abramowitz-Stegun 7.1.26 (|err|<=1.5e-7)
__device__ __forceinline__ float gelu_f(float x) {
    const float z = x * 0.70710678118654752f;
    const float az = fabsf(z);
    const float t = 1.f / (1.f + 0.3275911f * az);
    const float poly = t * (0.254829592f + t * (-0.284496736f +
                       t * (1.421413741f + t * (-1.453152027f + t * 1.061405429f))));
    const float e = __expf(-z * z);
    const float er = copysignf(1.f - poly * e, z);
    return 0.5f * x * (1.f + er);
}

// async global->LDS 16B/lane; LDS dest must be wave-uniform base + lane*16
__device__ __forceinline__ void gll16(const unsigned short* g, unsigned short* l) {
    __builtin_amdgcn_global_load_lds(
        (const __attribute__((address_space(1))) void*)g,
        (__attribute__((address_space(3))) void*)l,
        16, 0, 0);
}

// ---------------------------------------------------------------------------
// Swapped-operand bf16 GEMM, 512 threads, tile 128(M)x256(N), BK=64.
// Double-buffered LDS + counted-vmcnt 2-phase pipeline (T3+T4): stage tile
// t+1 while computing tile t; vmcnt(6) mid-loop (never 0); raw s_barrier.
// XOR-granule LDS swizzle (bank-conflict-free, gll16-compatible).
// EPI 1: + column sum-of-squares -> norm2        (G2)
// EPI 2: A reg-staged, scale -Pi*attn            (G3)   [reg pipeline]
// EPI 3: A reg-staged, LN+gelu via rowstats; + bf16 residual, fp32 out (G5)
// EPI 4: + per-row sum/sumsq -> rowstats         (G4)
// EPI 5: pair-interleaved [s;v] weights + in-lane rope epilogue        (G1)
// ---------------------------------------------------------------------------
template <int EPI, int KT, typename TOUT>
__global__ __launch_bounds__(512) void gemm_bf(
    const unsigned short* __restrict__ A0, int lda0,
    const unsigned short* __restrict__ A1, int lda1, int K0,
    const unsigned short* __restrict__ W,
    const float* __restrict__ bias,
    const unsigned short* __restrict__ resid_bf,   // EPI3
    const float* __restrict__ Pi,                  // EPI2
    const float* __restrict__ attnb,               // EPI2
    float* __restrict__ norm2,                     // EPI1
    float* __restrict__ rowstats,                  // EPI4 (write), EPI3 (read)
    const float* __restrict__ enc,                 // EPI5
    const float* __restrict__ lng,                 // EPI3
    const float* __restrict__ lnb,                 // EPI3
    TOUT* __restrict__ C, int N)
{
    constexpr int NT = KT / 64;
    constexpr bool REG = (EPI == 2) || (EPI == 3);
    __shared__ alignas(16) unsigned short As[2 * 128 * 64];
    __shared__ alignas(16) unsigned short Bs[2 * 256 * 64];

    const int t = threadIdx.x;
    const int bn = blockIdx.x, bm = blockIdx.y;
    const int lane = t & 63, wave = t >> 6;          // 8 waves
    const int wm = wave >> 2, wn = wave & 3;         // 2 x 4
    const int quad = lane >> 4, l16 = lane & 15;
    const int rt = t >> 3, st = t & 7;               // rt 0..63

    const int swz = (st ^ (rt & 7)) * 8;             // same for rows rt, rt+64
    const size_t g0 = (size_t)bm * 128 + rt;
    const size_t g1 = g0 + 64;

    float mean0 = 0.f, rstd0 = 0.f, mean1 = 0.f, rstd1 = 0.f;
    if constexpr (EPI == 3) {
        const float2 s0 = *(const float2*)(rowstats + g0 * 2);
        const float2 s1 = *(const float2*)(rowstats + g1 * 2);
        mean0 = s0.x * (1.f / 512.f);
        rstd0 = rsqrtf(s0.y * (1.f / 512.f) - mean0 * mean0 + 1e-5f);
        mean1 = s1.x * (1.f / 512.f);
        rstd1 = rsqrtf(s1.y * (1.f / 512.f) - mean1 * mean1 + 1e-5f);
    }

    floatx4 acc[4][4];
    #pragma unroll
    for (int i = 0; i < 4; ++i)
        #pragma unroll
        for (int j = 0; j < 4; ++j)
            acc[i][j] = (floatx4){0.f, 0.f, 0.f, 0.f};

    auto stageW = [&](int buf, int tt) {
        unsigned short* dst = Bs + buf * (256 * 64) + rt * 64 + st * 8;
        const unsigned short* src = W + ((size_t)bn * 256 + rt) * KT + tt * 64 + swz;
        #pragma unroll
        for (int hh = 0; hh < 4; ++hh)
            gll16(src + (size_t)hh * 64 * KT, dst + hh * 64 * 64);
    };
    auto stageA = [&](int buf, int tt) {             // !REG path
        const int col = tt * 64 + swz;
        unsigned short* dst = As + buf * (128 * 64) + rt * 64 + st * 8;
        const unsigned short* p0 = (col < K0) ? (A0 + g0 * (size_t)lda0 + col)
                                              : (A1 + g0 * (size_t)lda1 + (col - K0));
        const unsigned short* p1 = (col < K0) ? (A0 + g1 * (size_t)lda0 + col)
                                              : (A1 + g1 * (size_t)lda1 + (col - K0));
        gll16(p0, dst);
        gll16(p1, dst + 64 * 64);
    };
    auto loadA = [&](int tt, short8& r0, short8& r1) {   // REG path
        const int col = tt * 64 + swz;
        r0 = *(const short8*)(A0 + g0 * (size_t)lda0 + col);
        r1 = *(const short8*)(A0 + g1 * (size_t)lda0 + col);
    };
    auto xformWrite = [&](int buf, int tt, short8 r0, short8 r1) {
        unsigned short* d0 = As + buf * (128 * 64) + rt * 64 + st * 8;
        unsigned short* d1 = d0 + 64 * 64;
        if constexpr (EPI == 2) {
            const float asc = attnb[((bm >> 5) << 2) + tt];
            const float sc0 = -Pi[g0 * 4 + tt] * asc;
            const float sc1 = -Pi[g1 * 4 + tt] * asc;
            short8 o0, o1;
            #pragma unroll
            for (int j = 0; j < 8; ++j) {
                o0[j] = (short)f2bf(bf2f((unsigned short)r0[j]) * sc0);
                o1[j] = (short)f2bf(bf2f((unsigned short)r1[j]) * sc1);
            }
            *(short8*)d0 = o0; *(short8*)d1 = o1;
        } else {  // EPI == 3: LN(512)+gelu on the fly
            const int col = tt * 64 + swz;
            const float4 ga = *(const float4*)(lng + col);
            const float4 gb = *(const float4*)(lng + col + 4);
            const float4 ba = *(const float4*)(lnb + col);
            const float4 bb = *(const float4*)(lnb + col + 4);
            const float vg[8] = {ga.x, ga.y, ga.z, ga.w, gb.x, gb.y, gb.z, gb.w};
            const float vb[8] = {ba.x, ba.y, ba.z, ba.w, bb.x, bb.y, bb.z, bb.w};
            short8 o0, o1;
            #pragma unroll
            for (int j = 0; j < 8; ++j) {
                const float l0 = (bf2f((unsigned short)r0[j]) - mean0) * rstd0 * vg[j] + vb[j];
                const float l1 = (bf2f((unsigned short)r1[j]) - mean1) * rstd1 * vg[j] + vb[j];
                o0[j] = (short)f2bf(gelu_f(l0));
                o1[j] = (short)f2bf(gelu_f(l1));
            }
            *(short8*)d0 = o0; *(short8*)d1 = o1;
        }
    };
    auto compute = [&](int buf) {
        const unsigned short* Ab = As + buf * (128 * 64);
        const unsigned short* Bb = Bs + buf * (256 * 64);
        #pragma unroll
        for (int kk = 0; kk < 2; ++kk) {
            short8 af[4], wf[4];
            #pragma unroll
            for (int i = 0; i < 4; ++i) {
                const int ra = wm * 64 + i * 16 + l16;
                af[i] = *(const short8*)(Ab + ra * 64 + ((quad + kk * 4) ^ (ra & 7)) * 8);
                const int rw = wn * 64 + i * 16 + l16;
                wf[i] = *(const short8*)(Bb + rw * 64 + ((quad + kk * 4) ^ (rw & 7)) * 8);
            }
            #pragma unroll
            for (int mi = 0; mi < 4; ++mi)
                #pragma unroll
                for (int ni = 0; ni < 4; ++ni)
                    acc[mi][ni] = __builtin_amdgcn_mfma_f32_16x16x32_bf16(
                        wf[ni], af[mi], acc[mi][ni], 0, 0, 0);
        }
    };

    // ---- prologue: stage tile 0 (and prefetch A(1) regs for REG) ----
    short8 pa0, pa1;
    if constexpr (REG) {
        short8 c0, c1;
        loadA(0, c0, c1);
        CFENCE;
        stageW(0, 0);
        CFENCE;
        loadA(1, pa0, pa1);
        CFENCE;
        VMWAIT(6);              // A(0) regs ready (leaves W(0)+A(1) in flight)
        xformWrite(0, 0, c0, c1);
    } else {
        stageA(0, 0);
        stageW(0, 0);
        CFENCE;
    }

    // ---- pipelined main loop ----
    int cur = 0;
    #pragma unroll
    for (int tt = 0; tt < NT; ++tt) {
        const int nxt = cur ^ 1;
        if (tt + 1 < NT) {
            if constexpr (!REG) stageA(nxt, tt + 1);
            stageW(nxt, tt + 1);
            CFENCE;
            VMWAIT(6);          // tile tt fully landed; tile tt+1 (6 ops) in flight
        } else {
            VMWAIT(0);
        }
        LGKM0;
        BARRIER;                // E: tile tt visible to all waves
        if constexpr (REG) {
            if (tt + 1 < NT) {
                VMWAIT(4);      // A(tt+1) regs ready (leaves W(tt+1) in flight)
                xformWrite(nxt, tt + 1, pa0, pa1);
                if (tt + 2 < NT) { CFENCE; loadA(tt + 2, pa0, pa1); CFENCE; }
            }
        }
        compute(cur);
        if (tt + 1 < NT) {
            LGKM0;              // ds_write visibility before reuse
            BARRIER;            // G: all waves done reading cur
        }
        cur = nxt;
    }

    // epilogue: row = bm*128+wm*64+mi*16+l16; col = bn*256+wn*64+ni*16+quad*4+rg
    float rs[4], rq[4];
    if constexpr (EPI == 4) {
        #pragma unroll
        for (int m = 0; m < 4; ++m) { rs[m] = 0.f; rq[m] = 0.f; }
    }

    #pragma unroll
    for (int mi = 0; mi < 4; ++mi) {
        const size_t row = (size_t)bm * 128 + wm * 64 + mi * 16 + l16;
        #pragma unroll
        for (int ni = 0; ni < 4; ++ni) {
            const int cb = bn * 256 + wn * 64 + ni * 16 + quad * 4;
            const float4 b4 = *(const float4*)(bias + cb);
            if constexpr (EPI == 5) {
                // acc = {s_j, v_j, s_{j+1}, v_{j+1}}, j = cb/2 (even)
                const float s0 = acc[mi][ni][0] + b4.x;
                const float v0 = acc[mi][ni][1] + b4.y;
                const float s1 = acc[mi][ni][2] + b4.z;
                const float v1 = acc[mi][ni][3] + b4.w;
                const int j = cb >> 1;
                const int d = j & 63;
                const float2 e0 = *(const float2*)(enc + row * 64 + d);
                const float2 e1 = *(const float2*)(enc + 4194304 + row * 64 + d);
                const float r0 = s0 * e0.x - s1 * e1.x;
                const float r1 = s1 * e0.y + s0 * e1.y;
                ushort2 o;
                o.x = f2bf((r0 + v0) * (1.f / 3.f));
                o.y = f2bf((r1 + v1) * (1.f / 3.f));
                *(ushort2*)((unsigned short*)C + row * (size_t)N + j) = o;
            } else {
                float v[4] = {acc[mi][ni][0] + b4.x, acc[mi][ni][1] + b4.y,
                              acc[mi][ni][2] + b4.z, acc[mi][ni][3] + b4.w};
                if constexpr (EPI == 3) {
                    const ushort4 xr = *(const ushort4*)(resid_bf + row * (size_t)N + cb);
                    v[0] += bf2f(xr.x); v[1] += bf2f(xr.y);
                    v[2] += bf2f(xr.z); v[3] += bf2f(xr.w);
                }
                if constexpr (EPI == 4) {
                    #pragma unroll
                    for (int rg = 0; rg < 4; ++rg) { rs[mi] += v[rg]; rq[mi] += v[rg] * v[rg]; }
                }
                if constexpr (EPI == 1) {
                    float cs[4];
                    #pragma unroll
                    for (int rg = 0; rg < 4; ++rg) cs[rg] = v[rg] * v[rg];
                    #pragma unroll
                    for (int rg = 0; rg < 4; ++rg) {
                        float s = cs[rg];
                        s += __shfl_xor(s, 1, 64);
                        s += __shfl_xor(s, 2, 64);
                        s += __shfl_xor(s, 4, 64);
                        s += __shfl_xor(s, 8, 64);
                        if (l16 == 0) atomicAdd(&norm2[(bm >> 5) * 256 + cb + rg], s);
                    }
                }
                if constexpr (__is_same(TOUT, float)) {
                    float4 o; o.x = v[0]; o.y = v[1]; o.z = v[2]; o.w = v[3];
                    *(float4*)(C + row * (size_t)N + cb) = o;
                } else {
                    ushort4 o;
                    o.x = f2bf(v[0]); o.y = f2bf(v[1]); o.z = f2bf(v[2]); o.w = f2bf(v[3]);
                    *(ushort4*)(C + row * (size_t)N + cb) = o;
                }
            }
        }
    }
    if constexpr (EPI == 4) {
        #pragma unroll
        for (int mi = 0; mi < 4; ++mi) {
            float s = rs[mi], q = rq[mi];
            s += __shfl_xor(s, 16, 64); s += __shfl_xor(s, 32, 64);
            q += __shfl_xor(q, 16, 64); q += __shfl_xor(q, 32, 64);
            if (quad == 0) {
                const size_t row = (size_t)bm * 128 + wm * 64 + mi * 16 + l16;
                atomicAdd(&rowstats[row * 2], s);
                atomicAdd(&rowstats[row * 2 + 1], q);
            }
        }
    }
}

// ---------------------------------------------------------------------------
// single prep kernel: converts + fused weights + zeroing
// ---------------------------------------------------------------------------
__device__ __forceinline__ void conv8(const float* src, unsigned short* dst, int i) {
    const float4 f0 = *(const float4*)(src + (size_t)i * 8);
    const float4 f1 = *(const float4*)(src + (size_t)i * 8 + 4);
    short8 sv;
    sv[0] = (short)f2bf(f0.x); sv[1] = (short)f2bf(f0.y);
    sv[2] = (short)f2bf(f0.z); sv[3] = (short)f2bf(f0.w);
    sv[4] = (short)f2bf(f1.x); sv[5] = (short)f2bf(f1.y);
    sv[6] = (short)f2bf(f1.z); sv[7] = (short)f2bf(f1.w);
    *(short8*)(dst + (size_t)i * 8) = sv;
}

__global__ __launch_bounds__(256) void prep_all(
    const float* __restrict__ x, const float* __restrict__ Wqkv,
    const float* __restrict__ bqkv, const float* __restrict__ tssa_w,
    const float* __restrict__ op_w, const float* __restrict__ to_w,
    const float* __restrict__ to_b, const float* __restrict__ op_b,
    const float* __restrict__ f1w, const float* __restrict__ f2w,
    unsigned short* __restrict__ x_bf, unsigned short* __restrict__ Wsv,
    float* __restrict__ bsv, unsigned short* __restrict__ tssa_bf,
    unsigned short* __restrict__ Wf, float* __restrict__ bfb,
    unsigned short* __restrict__ ffn1_bf, unsigned short* __restrict__ ffn2_bf,
    float* __restrict__ zbase, float* __restrict__ rowstats)
{
    const int blk = blockIdx.x, tt = threadIdx.x;
    if (blk < 8192) {
        conv8(x, x_bf, blk * 256 + tt);
    } else if (blk < 8704) {
        // pair-interleaved: W'[2j] = Wq+Wk for out col j, W'[2j+1] = Wv
        const int r = blk - 8192, c = tt;      // r 0..511
        const int j = r >> 1;                  // out col 0..255
        const int h = j >> 6, dd = j & 63;
        const int base = h * 192 + dd * 3;
        if (!(r & 1)) {
            Wsv[r * 256 + c] = f2bf(Wqkv[(base + 0) * 256 + c] + Wqkv[(base + 1) * 256 + c]);
            if (c == 0) bsv[r] = bqkv[base] + bqkv[base + 1];
        } else {
            Wsv[r * 256 + c] = f2bf(Wqkv[(base + 2) * 256 + c]);
            if (c == 0) bsv[r] = bqkv[base + 2];
        }
    } else if (blk < 8960) {
        const int i = blk - 8704;
        float s = 0.f;
        for (int k = 0; k < 256; ++k) s += op_w[i * 256 + k] * to_w[k * 256 + tt];
        Wf[i * 256 + tt] = f2bf(s);
    } else if (blk == 8960) {
        float s = op_b[tt];
        for (int k = 0; k < 256; ++k) s += op_w[tt * 256 + k] * to_b[k];
        bfb[tt] = s;
    } else if (blk < 8993) {
        conv8(tssa_w, tssa_bf, (blk - 8961) * 256 + tt);
    } else if (blk < 9121) {
        conv8(f1w, ffn1_bf, (blk - 8993) * 256 + tt);
    } else if (blk < 9185) {
        conv8(f2w, ffn2_bf, (blk - 9121) * 256 + tt);
    } else {
        const int i = (blk - 9185) * 256 + tt;
        if (i < 4288) zbase[i] = 0.f;
        else if (i < 135360) rowstats[i - 4288] = 0.f;
    }
}

// ---------------------------------------------------------------------------
// per-row softmax over heads + S/T accumulation
// ---------------------------------------------------------------------------
__global__ __launch_bounds__(256) void pi_kernel(const unsigned short* __restrict__ w,
                                                 const float* __restrict__ norm2,
                                                 const float* __restrict__ temp,
                                                 float* __restrict__ Pi,
                                                 float* __restrict__ S,
                                                 float* __restrict__ T) {
    const int t = threadIdx.x;
    const int i = t & 15;
    const int lr = t >> 4;
    const size_t r = (size_t)blockIdx.x * 16 + lr;
    const int b = (int)(r >> 12);
    const unsigned short* wrow = w + r * 256;
    const float* n2row = norm2 + b * 256;
    float raw[4], nrm[4];
    #pragma unroll
    for (int h = 0; h < 4; ++h) {
        const ushort4 wv = *(const ushort4*)(wrow + h * 64 + i * 4);
        const float w0 = bf2f(wv.x), w1 = bf2f(wv.y), w2 = bf2f(wv.z), w3 = bf2f(wv.w);
        const float4 n2 = *(const float4*)(n2row + h * 64 + i * 4);
        const float s0 = w0 * w0, s1 = w1 * w1, s2 = w2 * w2, s3 = w3 * w3;
        raw[h] = s0 + s1 + s2 + s3;
        nrm[h] = s0 / fmaxf(n2.x, 1e-24f) + s1 / fmaxf(n2.y, 1e-24f)
               + s2 / fmaxf(n2.z, 1e-24f) + s3 / fmaxf(n2.w, 1e-24f);
    }
    #pragma unroll
    for (int off = 1; off < 16; off <<= 1) {
        #pragma unroll
        for (int h = 0; h < 4; ++h) {
            raw[h] += __shfl_xor(raw[h], off, 64);
            nrm[h] += __shfl_xor(nrm[h], off, 64);
        }
    }
    float sw[4], m = -1e30f;
    #pragma unroll
    for (int h = 0; h < 4; ++h) { sw[h] = nrm[h] * temp[h]; m = fmaxf(m, sw[h]); }
    float e[4], Z = 0.f;
    #pragma unroll
    for (int h = 0; h < 4; ++h) { e[h] = expf(sw[h] - m); Z += e[h]; }
    const float invZ = 1.f / Z;
    float pi[4];
    #pragma unroll
    for (int h = 0; h < 4; ++h) pi[h] = e[h] * invZ;
    if (i < 4) Pi[r * 4 + i] = pi[i];

    __shared__ float sS[16][4], sT[16][4];
    if (i == 0) {
        #pragma unroll
        for (int h = 0; h < 4; ++h) { sS[lr][h] = pi[h]; sT[lr][h] = pi[h] * raw[h]; }
    }
    __syncthreads();
    if (t < 4) {
        float as = 0.f, at = 0.f;
        for (int rr = 0; rr < 16; ++rr) { as += sS[rr][t]; at += sT[rr][t]; }
        atomicAdd(&S[b * 4 + t], as);
        atomicAdd(&T[b * 4 + t], at);
    }
}

__global__ void attn_kernel(const float* __restrict__ S, const float* __restrict__ T,
                            float* __restrict__ attn) {
    const int i = threadIdx.x;  // 64
    const float dots = T[i] / (S[i] + 1e-8f);
    attn[i] = 1.f / (1.f + dots);
}

// ---------------------------------------------------------------------------
extern "C" void kernel_launch(void* const* d_in, const int* in_sizes, int n_in,
                              void* d_out, int out_size, void* d_ws, size_t ws_size,
                              hipStream_t stream) {
    (void)in_sizes; (void)n_in; (void)out_size; (void)ws_size;
    const float* x          = (const float*)d_in[0];
    const float* enc        = (const float*)d_in[1];
    const float* Wqkv_w     = (const float*)d_in[2];
    const float* Wqkv_b     = (const float*)d_in[3];
    const float* tssa_qkv_w = (const float*)d_in[4];
    const float* tssa_qkv_b = (const float*)d_in[5];
    const float* temp       = (const float*)d_in[6];
    const float* tssa_out_w = (const float*)d_in[7];
    const float* tssa_out_b = (const float*)d_in[8];
    const float* out_proj_w = (const float*)d_in[9];
    const float* out_proj_b = (const float*)d_in[10];
    const float* ffn1_w     = (const float*)d_in[11];
    const float* ffn1_b     = (const float*)d_in[12];
    const float* ln_g       = (const float*)d_in[13];
    const float* ln_b       = (const float*)d_in[14];
    const float* ffn2_w     = (const float*)d_in[15];
    const float* ffn2_b     = (const float*)d_in[16];
    float* outp = (float*)d_out;

    const int M = Bc * Nc;  // 65536

    char* ws = (char*)d_ws;
    unsigned short* x_bf  = (unsigned short*)(ws);
    unsigned short* wi_bf = (unsigned short*)(ws + (size_t)(32 << 20));
    unsigned short* h1_bf = (unsigned short*)(ws + (size_t)(32 << 20));
    unsigned short* w_bf  = (unsigned short*)(ws + (size_t)(64 << 20));
    unsigned short* msg_bf= (unsigned short*)(ws + (size_t)(96 << 20));
    float* fb    = (float*)(ws + (size_t)(128 << 20));
    float* Pi    = fb;                 // 262144
    float* norm2 = Pi + 262144;        // 4096  <- zero base
    float* Sb    = norm2 + 4096;       // 64
    float* Tb    = Sb + 64;            // 64
    float* attnb = Tb + 64;            // 64
    float* bsv   = attnb + 64;         // 512
    float* bfb   = bsv + 512;          // 256
    float* rowstats = bfb + 256;       // 131072
    unsigned short* Wsv_bf  = (unsigned short*)(rowstats + 131072);
    unsigned short* tssa_bf = Wsv_bf + 131072;
    unsigned short* Wf_bf   = tssa_bf + 65536;
    unsigned short* ffn1_bf = Wf_bf + 65536;
    unsigned short* ffn2_bf = ffn1_bf + 262144;

    // 1. prep
    prep_all<<<9714, 256, 0, stream>>>(
        x, Wqkv_w, Wqkv_b, tssa_qkv_w, out_proj_w, tssa_out_w, tssa_out_b,
        out_proj_b, ffn1_w, ffn2_w,
        x_bf, Wsv_bf, bsv, tssa_bf, Wf_bf, bfb, ffn1_bf, ffn2_bf,
        norm2, rowstats);

    // 2. G1: wi = rope-combine(x_bf @ Wsv'^T + b), pair-interleaved weights
    gemm_bf<5, 256, unsigned short><<<dim3(2, M / 128), 512, 0, stream>>>(
        x_bf, 256, x_bf, 256, 256, Wsv_bf, bsv,
        nullptr, nullptr, nullptr, nullptr, nullptr,
        enc, nullptr, nullptr, wi_bf, 256);

    // 3. G2: w = wi @ tssa^T + b -> bf16, fused colsq -> norm2
    gemm_bf<1, 256, unsigned short><<<dim3(1, M / 128), 512, 0, stream>>>(
        wi_bf, 256, wi_bf, 256, 256, tssa_bf, tssa_qkv_b,
        nullptr, nullptr, nullptr, norm2, nullptr,
        nullptr, nullptr, nullptr, w_bf, 256);

    // 4/5. stats
    pi_kernel<<<4096, 256, 0, stream>>>(w_bf, norm2, temp, Pi, Sb, Tb);
    attn_kernel<<<1, 64, 0, stream>>>(Sb, Tb, attnb);

    // 6. G3: message = (-w*Pi*attn) @ Wf^T + bfb
    gemm_bf<2, 256, unsigned short><<<dim3(1, M / 128), 512, 0, stream>>>(
        w_bf, 256, w_bf, 256, 256, Wf_bf, bfb,
        nullptr, Pi, attnb, nullptr, nullptr,
        nullptr, nullptr, nullptr, msg_bf, 256);

    // 7. G4: h1 = [x_bf, msg] @ ffn1^T + b -> bf16, fused row sum/sumsq
    gemm_bf<4, 512, unsigned short><<<dim3(2, M / 128), 512, 0, stream>>>(
        x_bf, 256, msg_bf, 256, 256, ffn1_bf, ffn1_b,
        nullptr, nullptr, nullptr, nullptr, rowstats,
        nullptr, nullptr, nullptr, h1_bf, 512);

    // 8. G5: out = x + gelu(LN(h1)) @ ffn2^T + b
    //    LN+gelu fused into pipelined A-staging (rowstats from G4)
    gemm_bf<3, 512, float><<<dim3(1, M / 128), 512, 0, stream>>>(
        h1_bf, 512, h1_bf, 512, 512, ffn2_bf, ffn2_b,
        x_bf, nullptr, nullptr, nullptr, rowstats,
        nullptr, ln_g, ln_b, outp, 256);
}

// Round 3
// 465.400 us; speedup vs baseline: 1.1756x; 1.1756x over previous
//
#include <hip/hip_runtime.h>
#include <math.h>

#define Bc 16
#define Nc 4096

typedef __attribute__((ext_vector_type(8))) short short8;
typedef __attribute__((ext_vector_type(4))) float floatx4;

__device__ __forceinline__ unsigned short f2bf(float f) {
    union { float f; unsigned int u; } v; v.f = f;
    unsigned int u = v.u;
    return (unsigned short)((u + 0x7fffu + ((u >> 16) & 1u)) >> 16);
}
__device__ __forceinline__ float bf2f(unsigned short u) {
    union { unsigned int u; float f; } v; v.u = ((unsigned int)u) << 16;
    return v.f;
}

// branch-free gelu: erf via Abramowitz-Stegun 7.1.26 (|err|<=1.5e-7)
// validated round 2: absmax identical to libm erff path
__device__ __forceinline__ float gelu_f(float x) {
    const float z = x * 0.70710678118654752f;
    const float az = fabsf(z);
    const float t = 1.f / (1.f + 0.3275911f * az);
    const float poly = t * (0.254829592f + t * (-0.284496736f +
                       t * (1.421413741f + t * (-1.453152027f + t * 1.061405429f))));
    const float e = __expf(-z * z);
    const float er = copysignf(1.f - poly * e, z);
    return 0.5f * x * (1.f + er);
}

// async global->LDS 16B/lane; LDS dest must be wave-uniform base + lane*16
__device__ __forceinline__ void gll16(const unsigned short* g, unsigned short* l) {
    __builtin_amdgcn_global_load_lds(
        (const __attribute__((address_space(1))) void*)g,
        (__attribute__((address_space(3))) void*)l,
        16, 0, 0);
}

// ---------------------------------------------------------------------------
// Swapped-operand bf16 GEMM, 512 threads, tile 128(M)x256(N), BK=64.
// Single-buffered LDS (48KB -> 2-3 blocks/CU; cross-block wave overlap hides
// barrier drains per m114 -- explicit dbuf regressed, round 2).
// XOR-granule LDS swizzle (bank-conflict-free, gll16-compatible).
// EPI 1: + column sum-of-squares -> norm2        (G2)
// EPI 2: A staged with scale -Pi*attn, attn computed inline from S,T (G3)
// EPI 3: A staged with LN+gelu_f (rowstats); + bf16 residual, fp32 out (G5)
// EPI 4: + per-row sum/sumsq -> rowstats         (G4)
// EPI 5: pair-interleaved [s;v] weights + in-lane rope epilogue        (G1)
// ---------------------------------------------------------------------------
template <int EPI, typename TOUT>
__global__ __launch_bounds__(512) void gemm_bf(
    const unsigned short* __restrict__ A0, int lda0,
    const unsigned short* __restrict__ A1, int lda1, int K0,
    const unsigned short* __restrict__ W,
    const float* __restrict__ bias,
    const unsigned short* __restrict__ resid_bf,   // EPI3
    const float* __restrict__ Pi,                  // EPI2
    const float* __restrict__ Sb,                  // EPI2
    const float* __restrict__ Tb,                  // EPI2
    float* __restrict__ norm2,                     // EPI1
    float* __restrict__ rowstats,                  // EPI4 (write), EPI3 (read)
    const float* __restrict__ enc,                 // EPI5
    const float* __restrict__ lng,                 // EPI3
    const float* __restrict__ lnb,                 // EPI3
    TOUT* __restrict__ C, int N, int K)
{
    __shared__ alignas(16) unsigned short As[128 * 64];
    __shared__ alignas(16) unsigned short Bs[256 * 64];

    const int t = threadIdx.x;
    const int bn = blockIdx.x, bm = blockIdx.y;
    const int lane = t & 63, wave = t >> 6;          // 8 waves
    const int wm = wave >> 2, wn = wave & 3;         // 2 x 4
    const int quad = lane >> 4, l16 = lane & 15;
    const int rt = t >> 3, st = t & 7;               // rt 0..63

    float mean0 = 0.f, rstd0 = 0.f, mean1 = 0.f, rstd1 = 0.f;
    if constexpr (EPI == 3) {
        const size_t g0 = (size_t)bm * 128 + rt;
        const float2 s0 = *(const float2*)(rowstats + g0 * 2);
        const float2 s1 = *(const float2*)(rowstats + (g0 + 64) * 2);
        mean0 = s0.x * (1.f / 512.f);
        rstd0 = rsqrtf(s0.y * (1.f / 512.f) - mean0 * mean0 + 1e-5f);
        mean1 = s1.x * (1.f / 512.f);
        rstd1 = rsqrtf(s1.y * (1.f / 512.f) - mean1 * mean1 + 1e-5f);
    }

    floatx4 acc[4][4];
    #pragma unroll
    for (int i = 0; i < 4; ++i)
        #pragma unroll
        for (int j = 0; j < 4; ++j)
            acc[i][j] = (floatx4){0.f, 0.f, 0.f, 0.f};

    for (int k0 = 0; k0 < K; k0 += 64) {
        // A tile: 128 rows x 64
        #pragma unroll
        for (int hh = 0; hh < 2; ++hh) {
            const int row = hh * 64 + rt;
            const int col = k0 + (st ^ (row & 7)) * 8;
            unsigned short* ldsa = As + row * 64 + st * 8;
            const size_t grow = (size_t)bm * 128 + row;
            if constexpr (EPI == 2) {
                const int b = (int)(grow >> 12);
                const int hd = col >> 6;
                const float Sv = Sb[b * 4 + hd], Tv = Tb[b * 4 + hd];
                const float at = 1.f / (1.f + Tv / (Sv + 1e-8f));
                const float sc = -Pi[grow * 4 + hd] * at;
                const short8 a = *(const short8*)(A0 + grow * (size_t)lda0 + col);
                short8 o;
                #pragma unroll
                for (int j = 0; j < 8; ++j) o[j] = (short)f2bf(bf2f((unsigned short)a[j]) * sc);
                *(short8*)ldsa = o;
            } else if constexpr (EPI == 3) {
                // fused LayerNorm(512) + gelu on the fly (stats precomputed)
                const float mean = hh ? mean1 : mean0;
                const float rstd = hh ? rstd1 : rstd0;
                const short8 a = *(const short8*)(A0 + grow * (size_t)lda0 + col);
                const float4 ga = *(const float4*)(lng + col);
                const float4 gb = *(const float4*)(lng + col + 4);
                const float4 ba = *(const float4*)(lnb + col);
                const float4 bb = *(const float4*)(lnb + col + 4);
                const float vg[8] = {ga.x, ga.y, ga.z, ga.w, gb.x, gb.y, gb.z, gb.w};
                const float vb[8] = {ba.x, ba.y, ba.z, ba.w, bb.x, bb.y, bb.z, bb.w};
                short8 o;
                #pragma unroll
                for (int jj = 0; jj < 8; ++jj) {
                    const float ln = (bf2f((unsigned short)a[jj]) - mean) * rstd * vg[jj] + vb[jj];
                    o[jj] = (short)f2bf(gelu_f(ln));
                }
                *(short8*)ldsa = o;
            } else {
                const unsigned short* src = (col < K0)
                    ? (A0 + grow * (size_t)lda0 + col)
                    : (A1 + grow * (size_t)lda1 + (col - K0));
                gll16(src, ldsa);
            }
        }
        // W tile: 256 rows x 64
        #pragma unroll
        for (int hh = 0; hh < 4; ++hh) {
            const int row = hh * 64 + rt;
            const int col = k0 + (st ^ (row & 7)) * 8;
            gll16(W + ((size_t)bn * 256 + row) * (size_t)K + col, Bs + row * 64 + st * 8);
        }
        __syncthreads();
        #pragma unroll
        for (int kk = 0; kk < 2; ++kk) {
            short8 af[4], wf[4];
            #pragma unroll
            for (int i = 0; i < 4; ++i) {
                const int ra = wm * 64 + i * 16 + l16;
                af[i] = *(const short8*)(As + ra * 64 + ((quad + kk * 4) ^ (ra & 7)) * 8);
                const int rw = wn * 64 + i * 16 + l16;
                wf[i] = *(const short8*)(Bs + rw * 64 + ((quad + kk * 4) ^ (rw & 7)) * 8);
            }
            #pragma unroll
            for (int mi = 0; mi < 4; ++mi)
                #pragma unroll
                for (int ni = 0; ni < 4; ++ni)
                    acc[mi][ni] = __builtin_amdgcn_mfma_f32_16x16x32_bf16(
                        wf[ni], af[mi], acc[mi][ni], 0, 0, 0);
        }
        __syncthreads();
    }

    // epilogue: row = bm*128+wm*64+mi*16+l16; col = bn*256+wn*64+ni*16+quad*4+rg
    float rs[4], rq[4];
    if constexpr (EPI == 4) {
        #pragma unroll
        for (int m = 0; m < 4; ++m) { rs[m] = 0.f; rq[m] = 0.f; }
    }

    #pragma unroll
    for (int mi = 0; mi < 4; ++mi) {
        const size_t row = (size_t)bm * 128 + wm * 64 + mi * 16 + l16;
        #pragma unroll
        for (int ni = 0; ni < 4; ++ni) {
            const int cb = bn * 256 + wn * 64 + ni * 16 + quad * 4;
            const float4 b4 = *(const float4*)(bias + cb);
            if constexpr (EPI == 5) {
                // acc = {s_j, v_j, s_{j+1}, v_{j+1}}, j = cb/2 (even)
                const float s0 = acc[mi][ni][0] + b4.x;
                const float v0 = acc[mi][ni][1] + b4.y;
                const float s1 = acc[mi][ni][2] + b4.z;
                const float v1 = acc[mi][ni][3] + b4.w;
                const int j = cb >> 1;
                const int d = j & 63;
                const float2 e0 = *(const float2*)(enc + row * 64 + d);
                const float2 e1 = *(const float2*)(enc + 4194304 + row * 64 + d);
                const float r0 = s0 * e0.x - s1 * e1.x;
                const float r1 = s1 * e0.y + s0 * e1.y;
                ushort2 o;
                o.x = f2bf((r0 + v0) * (1.f / 3.f));
                o.y = f2bf((r1 + v1) * (1.f / 3.f));
                *(ushort2*)((unsigned short*)C + row * (size_t)N + j) = o;
            } else {
                float v[4] = {acc[mi][ni][0] + b4.x, acc[mi][ni][1] + b4.y,
                              acc[mi][ni][2] + b4.z, acc[mi][ni][3] + b4.w};
                if constexpr (EPI == 3) {
                    const ushort4 xr = *(const ushort4*)(resid_bf + row * (size_t)N + cb);
                    v[0] += bf2f(xr.x); v[1] += bf2f(xr.y);
                    v[2] += bf2f(xr.z); v[3] += bf2f(xr.w);
                }
                if constexpr (EPI == 4) {
                    #pragma unroll
                    for (int rg = 0; rg < 4; ++rg) { rs[mi] += v[rg]; rq[mi] += v[rg] * v[rg]; }
                }
                if constexpr (EPI == 1) {
                    float cs[4];
                    #pragma unroll
                    for (int rg = 0; rg < 4; ++rg) cs[rg] = v[rg] * v[rg];
                    #pragma unroll
                    for (int rg = 0; rg < 4; ++rg) {
                        float s = cs[rg];
                        s += __shfl_xor(s, 1, 64);
                        s += __shfl_xor(s, 2, 64);
                        s += __shfl_xor(s, 4, 64);
                        s += __shfl_xor(s, 8, 64);
                        if (l16 == 0) atomicAdd(&norm2[(bm >> 5) * 256 + cb + rg], s);
                    }
                }
                if constexpr (__is_same(TOUT, float)) {
                    float4 o; o.x = v[0]; o.y = v[1]; o.z = v[2]; o.w = v[3];
                    *(float4*)(C + row * (size_t)N + cb) = o;
                } else {
                    ushort4 o;
                    o.x = f2bf(v[0]); o.y = f2bf(v[1]); o.z = f2bf(v[2]); o.w = f2bf(v[3]);
                    *(ushort4*)(C + row * (size_t)N + cb) = o;
                }
            }
        }
    }
    if constexpr (EPI == 4) {
        #pragma unroll
        for (int mi = 0; mi < 4; ++mi) {
            float s = rs[mi], q = rq[mi];
            s += __shfl_xor(s, 16, 64); s += __shfl_xor(s, 32, 64);
            q += __shfl_xor(q, 16, 64); q += __shfl_xor(q, 32, 64);
            if (quad == 0) {
                const size_t row = (size_t)bm * 128 + wm * 64 + mi * 16 + l16;
                atomicAdd(&rowstats[row * 2], s);
                atomicAdd(&rowstats[row * 2 + 1], q);
            }
        }
    }
}

// ---------------------------------------------------------------------------
// single prep kernel: converts + fused weights + zeroing
// ---------------------------------------------------------------------------
__device__ __forceinline__ void conv8(const float* src, unsigned short* dst, int i) {
    const float4 f0 = *(const float4*)(src + (size_t)i * 8);
    const float4 f1 = *(const float4*)(src + (size_t)i * 8 + 4);
    short8 sv;
    sv[0] = (short)f2bf(f0.x); sv[1] = (short)f2bf(f0.y);
    sv[2] = (short)f2bf(f0.z); sv[3] = (short)f2bf(f0.w);
    sv[4] = (short)f2bf(f1.x); sv[5] = (short)f2bf(f1.y);
    sv[6] = (short)f2bf(f1.z); sv[7] = (short)f2bf(f1.w);
    *(short8*)(dst + (size_t)i * 8) = sv;
}

__global__ __launch_bounds__(256) void prep_all(
    const float* __restrict__ x, const float* __restrict__ Wqkv,
    const float* __restrict__ bqkv, const float* __restrict__ tssa_w,
    const float* __restrict__ op_w, const float* __restrict__ to_w,
    const float* __restrict__ to_b, const float* __restrict__ op_b,
    const float* __restrict__ f1w, const float* __restrict__ f2w,
    unsigned short* __restrict__ x_bf, unsigned short* __restrict__ Wsv,
    float* __restrict__ bsv, unsigned short* __restrict__ tssa_bf,
    unsigned short* __restrict__ Wf, float* __restrict__ bfb,
    unsigned short* __restrict__ ffn1_bf, unsigned short* __restrict__ ffn2_bf,
    float* __restrict__ zbase, float* __restrict__ rowstats)
{
    const int blk = blockIdx.x, tt = threadIdx.x;
    if (blk < 8192) {
        conv8(x, x_bf, blk * 256 + tt);
    } else if (blk < 8704) {
        // pair-interleaved: W'[2j] = Wq+Wk for out col j, W'[2j+1] = Wv
        const int r = blk - 8192, c = tt;      // r 0..511
        const int j = r >> 1;                  // out col 0..255
        const int h = j >> 6, dd = j & 63;
        const int base = h * 192 + dd * 3;
        if (!(r & 1)) {
            Wsv[r * 256 + c] = f2bf(Wqkv[(base + 0) * 256 + c] + Wqkv[(base + 1) * 256 + c]);
            if (c == 0) bsv[r] = bqkv[base] + bqkv[base + 1];
        } else {
            Wsv[r * 256 + c] = f2bf(Wqkv[(base + 2) * 256 + c]);
            if (c == 0) bsv[r] = bqkv[base + 2];
        }
    } else if (blk < 8960) {
        const int i = blk - 8704;
        float s = 0.f;
        for (int k = 0; k < 256; ++k) s += op_w[i * 256 + k] * to_w[k * 256 + tt];
        Wf[i * 256 + tt] = f2bf(s);
    } else if (blk == 8960) {
        float s = op_b[tt];
        for (int k = 0; k < 256; ++k) s += op_w[tt * 256 + k] * to_b[k];
        bfb[tt] = s;
    } else if (blk < 8993) {
        conv8(tssa_w, tssa_bf, (blk - 8961) * 256 + tt);
    } else if (blk < 9121) {
        conv8(f1w, ffn1_bf, (blk - 8993) * 256 + tt);
    } else if (blk < 9185) {
        conv8(f2w, ffn2_bf, (blk - 9121) * 256 + tt);
    } else {
        const int i = (blk - 9185) * 256 + tt;
        if (i < 4288) zbase[i] = 0.f;
        else if (i < 135360) rowstats[i - 4288] = 0.f;
    }
}

// ---------------------------------------------------------------------------
// per-row softmax over heads + S/T accumulation
// ---------------------------------------------------------------------------
__global__ __launch_bounds__(256) void pi_kernel(const unsigned short* __restrict__ w,
                                                 const float* __restrict__ norm2,
                                                 const float* __restrict__ temp,
                                                 float* __restrict__ Pi,
                                                 float* __restrict__ S,
                                                 float* __restrict__ T) {
    const int t = threadIdx.x;
    const int i = t & 15;
    const int lr = t >> 4;
    const size_t r = (size_t)blockIdx.x * 16 + lr;
    const int b = (int)(r >> 12);
    const unsigned short* wrow = w + r * 256;
    const float* n2row = norm2 + b * 256;
    float raw[4], nrm[4];
    #pragma unroll
    for (int h = 0; h < 4; ++h) {
        const ushort4 wv = *(const ushort4*)(wrow + h * 64 + i * 4);
        const float w0 = bf2f(wv.x), w1 = bf2f(wv.y), w2 = bf2f(wv.z), w3 = bf2f(wv.w);
        const float4 n2 = *(const float4*)(n2row + h * 64 + i * 4);
        const float s0 = w0 * w0, s1 = w1 * w1, s2 = w2 * w2, s3 = w3 * w3;
        raw[h] = s0 + s1 + s2 + s3;
        nrm[h] = s0 / fmaxf(n2.x, 1e-24f) + s1 / fmaxf(n2.y, 1e-24f)
               + s2 / fmaxf(n2.z, 1e-24f) + s3 / fmaxf(n2.w, 1e-24f);
    }
    #pragma unroll
    for (int off = 1; off < 16; off <<= 1) {
        #pragma unroll
        for (int h = 0; h < 4; ++h) {
            raw[h] += __shfl_xor(raw[h], off, 64);
            nrm[h] += __shfl_xor(nrm[h], off, 64);
        }
    }
    float sw[4], m = -1e30f;
    #pragma unroll
    for (int h = 0; h < 4; ++h) { sw[h] = nrm[h] * temp[h]; m = fmaxf(m, sw[h]); }
    float e[4], Z = 0.f;
    #pragma unroll
    for (int h = 0; h < 4; ++h) { e[h] = expf(sw[h] - m); Z += e[h]; }
    const float invZ = 1.f / Z;
    float pi[4];
    #pragma unroll
    for (int h = 0; h < 4; ++h) pi[h] = e[h] * invZ;
    if (i < 4) Pi[r * 4 + i] = pi[i];

    __shared__ float sS[16][4], sT[16][4];
    if (i == 0) {
        #pragma unroll
        for (int h = 0; h < 4; ++h) { sS[lr][h] = pi[h]; sT[lr][h] = pi[h] * raw[h]; }
    }
    __syncthreads();
    if (t < 4) {
        float as = 0.f, at = 0.f;
        for (int rr = 0; rr < 16; ++rr) { as += sS[rr][t]; at += sT[rr][t]; }
        atomicAdd(&S[b * 4 + t], as);
        atomicAdd(&T[b * 4 + t], at);
    }
}

// ---------------------------------------------------------------------------
extern "C" void kernel_launch(void* const* d_in, const int* in_sizes, int n_in,
                              void* d_out, int out_size, void* d_ws, size_t ws_size,
                              hipStream_t stream) {
    (void)in_sizes; (void)n_in; (void)out_size; (void)ws_size;
    const float* x          = (const float*)d_in[0];
    const float* enc        = (const float*)d_in[1];
    const float* Wqkv_w     = (const float*)d_in[2];
    const float* Wqkv_b     = (const float*)d_in[3];
    const float* tssa_qkv_w = (const float*)d_in[4];
    const float* tssa_qkv_b = (const float*)d_in[5];
    const float* temp       = (const float*)d_in[6];
    const float* tssa_out_w = (const float*)d_in[7];
    const float* tssa_out_b = (const float*)d_in[8];
    const float* out_proj_w = (const float*)d_in[9];
    const float* out_proj_b = (const float*)d_in[10];
    const float* ffn1_w     = (const float*)d_in[11];
    const float* ffn1_b     = (const float*)d_in[12];
    const float* ln_g       = (const float*)d_in[13];
    const float* ln_b       = (const float*)d_in[14];
    const float* ffn2_w     = (const float*)d_in[15];
    const float* ffn2_b     = (const float*)d_in[16];
    float* outp = (float*)d_out;

    const int M = Bc * Nc;  // 65536

    char* ws = (char*)d_ws;
    unsigned short* x_bf  = (unsigned short*)(ws);
    unsigned short* wi_bf = (unsigned short*)(ws + (size_t)(32 << 20));
    unsigned short* h1_bf = (unsigned short*)(ws + (size_t)(32 << 20));
    unsigned short* w_bf  = (unsigned short*)(ws + (size_t)(64 << 20));
    unsigned short* msg_bf= (unsigned short*)(ws + (size_t)(96 << 20));
    float* fb    = (float*)(ws + (size_t)(128 << 20));
    float* Pi    = fb;                 // 262144
    float* norm2 = Pi + 262144;        // 4096  <- zero base
    float* Sb    = norm2 + 4096;       // 64
    float* Tb    = Sb + 64;            // 64
    float* attnb = Tb + 64;            // 64 (unused, kept for layout)
    float* bsv   = attnb + 64;         // 512
    float* bfb   = bsv + 512;          // 256
    float* rowstats = bfb + 256;       // 131072
    unsigned short* Wsv_bf  = (unsigned short*)(rowstats + 131072);
    unsigned short* tssa_bf = Wsv_bf + 131072;
    unsigned short* Wf_bf   = tssa_bf + 65536;
    unsigned short* ffn1_bf = Wf_bf + 65536;
    unsigned short* ffn2_bf = ffn1_bf + 262144;

    // 1. prep
    prep_all<<<9714, 256, 0, stream>>>(
        x, Wqkv_w, Wqkv_b, tssa_qkv_w, out_proj_w, tssa_out_w, tssa_out_b,
        out_proj_b, ffn1_w, ffn2_w,
        x_bf, Wsv_bf, bsv, tssa_bf, Wf_bf, bfb, ffn1_bf, ffn2_bf,
        norm2, rowstats);

    // 2. G1: wi = rope-combine(x_bf @ Wsv'^T + b), pair-interleaved weights
    gemm_bf<5, unsigned short><<<dim3(2, M / 128), 512, 0, stream>>>(
        x_bf, 256, x_bf, 256, 256, Wsv_bf, bsv,
        nullptr, nullptr, nullptr, nullptr, nullptr, nullptr,
        enc, nullptr, nullptr, wi_bf, 256, 256);

    // 3. G2: w = wi @ tssa^T + b -> bf16, fused colsq -> norm2
    gemm_bf<1, unsigned short><<<dim3(1, M / 128), 512, 0, stream>>>(
        wi_bf, 256, wi_bf, 256, 256, tssa_bf, tssa_qkv_b,
        nullptr, nullptr, nullptr, nullptr, norm2, nullptr,
        nullptr, nullptr, nullptr, w_bf, 256, 256);

    // 4. stats (attn folded into G3's staging)
    pi_kernel<<<4096, 256, 0, stream>>>(w_bf, norm2, temp, Pi, Sb, Tb);

    // 5. G3: message = (-w*Pi*attn) @ Wf^T + bfb, attn = 1/(1+T/(S+eps)) inline
    gemm_bf<2, unsigned short><<<dim3(1, M / 128), 512, 0, stream>>>(
        w_bf, 256, w_bf, 256, 256, Wf_bf, bfb,
        nullptr, Pi, Sb, Tb, nullptr, nullptr,
        nullptr, nullptr, nullptr, msg_bf, 256, 256);

    // 6. G4: h1 = [x_bf, msg] @ ffn1^T + b -> bf16, fused row sum/sumsq
    gemm_bf<4, unsigned short><<<dim3(2, M / 128), 512, 0, stream>>>(
        x_bf, 256, msg_bf, 256, 256, ffn1_bf, ffn1_b,
        nullptr, nullptr, nullptr, nullptr, nullptr, rowstats,
        nullptr, nullptr, nullptr, h1_bf, 512, 512);

    // 7. G5: out = x + gelu_f(LN(h1)) @ ffn2^T + b (fused into A-staging)
    gemm_bf<3, float><<<dim3(1, M / 128), 512, 0, stream>>>(
        h1_bf, 512, h1_bf, 512, 512, ffn2_bf, ffn2_b,
        x_bf, nullptr, nullptr, nullptr, nullptr, rowstats,
        nullptr, ln_g, ln_b, outp, 256, 512);
}